// Round 4
// baseline (2656.144 us; speedup 1.0000x reference)
//
#include <hip/hip_runtime.h>
#include <hip/hip_bf16.h>
#include <cmath>

typedef __hip_bfloat16 bf16;
typedef __attribute__((ext_vector_type(4))) float floatx4;
typedef __attribute__((ext_vector_type(8))) __bf16 bf16x8;
typedef __attribute__((ext_vector_type(8))) unsigned short ushortx8;
typedef __attribute__((ext_vector_type(4))) unsigned short ushortx4;

#define DEV __device__ __forceinline__

DEV float b2f(unsigned short u){ union{unsigned int i; float f;} v; v.i=((unsigned int)u)<<16; return v.f; }
DEV float sigf(float x){ return 1.0f/(1.0f+__expf(-x)); }
DEV float geluf(float x){ return 0.5f*x*(1.0f+erff(x*0.7071067811865475f)); }
DEV unsigned short f2b(float f){ bf16 b = __float2bfloat16(f); unsigned short u;
                                __builtin_memcpy(&u,&b,2); return u; }

// async global->LDS, 16B per lane. LDS dest: WAVE-UNIFORM base; HW writes each
// lane at base + lane*16B. Global src is per-lane.
#define GLL16(g,l) __builtin_amdgcn_global_load_lds( \
  (const __attribute__((address_space(1))) unsigned int*)(g), \
  (__attribute__((address_space(3))) unsigned int*)(l), 16, 0, 0)

// ---------------------------------------------------------------------------
// fp32 -> bf16 weight convert, 8 elems/thread
// ---------------------------------------------------------------------------
__global__ __launch_bounds__(256)
void w2b_kernel(const float* __restrict__ in, bf16* __restrict__ out)
{
  long i = ((long)blockIdx.x*256 + threadIdx.x)*8;
  float4 a = *(const float4*)(in+i);
  float4 b = *(const float4*)(in+i+4);
  ushortx8 o;
  o[0]=f2b(a.x); o[1]=f2b(a.y); o[2]=f2b(a.z); o[3]=f2b(a.w);
  o[4]=f2b(b.x); o[5]=f2b(b.y); o[6]=f2b(b.z); o[7]=f2b(b.w);
  *(ushortx8*)((unsigned short*)out + i) = o;
}

// ---------------------------------------------------------------------------
// Generic MFMA GEMM:  C[M,N] = A[M,K] * B[N,K]^T  (both K-contiguous, bf16)
// 128x128 tile, BK=32, 256 threads (2x2 waves, each 64x64 via 4x4 16x16x32).
// 2-PHASE double-buffered schedule (T3 minimum recipe): issue next tile's
// global_load_lds BEFORE computing current tile; ONE barrier per K-step.
// The barrier's vmcnt(0) drain is covered by the ds_read+MFMA phase.
// Requires K % 64 == 0 (true for all call sites: 128, 1536, 3072).
// MODE: 0=plain(+bias)  3=mul*sigmoid(acc+bias)
//       4=resid: x32 = (xin?xin:x32) + gate[row]*(acc+bias); opt fp32 fout store
//       5=GLU: out = accB * sigmoid(accB2)   (dual B tiles)
// ---------------------------------------------------------------------------
template<int MODE>
__global__ __launch_bounds__(256)
void gemm_bt(const bf16* __restrict__ A, int lda, long astr,
             const bf16* __restrict__ B, int ldb, long bstr,
             const bf16* __restrict__ B2,
             int K,
             const float* __restrict__ bias,
             const bf16* __restrict__ mul, int ldm,
             const float* __restrict__ gate,
             const float* __restrict__ xin,
             float* __restrict__ x32, int ldx,
             bf16* __restrict__ outb, int ldc, long cstr,
             float* __restrict__ fout)
{
  __shared__ __align__(16) unsigned short As[2][128*32];
  __shared__ __align__(16) unsigned short Bs[2][128*32];
  __shared__ __align__(16) unsigned short Bs2[(MODE==5)?2:1][(MODE==5)?128*32:16];
  const int bz = blockIdx.z;
  const unsigned short* Ag = (const unsigned short*)A + (long)bz*astr;
  const unsigned short* Bg = (const unsigned short*)B + (long)bz*bstr;
  const int bm = blockIdx.x*128, bn = blockIdx.y*128;
  const int tid = threadIdx.x, lane = tid&63, wv = tid>>6;
  const int wm = (wv&1)*64, wn = (wv>>1)*64;
  const int fr = lane&15, fq = lane>>4;
  floatx4 acc[4][4];
  floatx4 acc2[(MODE==5)?4:1][(MODE==5)?4:1];
  floatx4 zero = {0.0f,0.0f,0.0f,0.0f};
#pragma unroll
  for (int i=0;i<4;i++)
#pragma unroll
    for (int j=0;j<4;j++) acc[i][j]=zero;
  if (MODE==5){
#pragma unroll
    for (int i=0;i<4;i++)
#pragma unroll
      for (int j=0;j<4;j++) acc2[i][j]=zero;
  }
  const int sr = tid>>2, sc = (tid&3)*8;
  const unsigned short* ap0 = Ag + (long)(bm+sr)*lda + sc;
  const unsigned short* ap1 = Ag + (long)(bm+sr+64)*lda + sc;
  const unsigned short* bp0 = Bg + (long)(bn+sr)*ldb + sc;
  const unsigned short* bp1 = Bg + (long)(bn+sr+64)*ldb + sc;
  const unsigned short* cp0 = (MODE==5)? (const unsigned short*)B2 + (long)(bn+sr)*ldb + sc : nullptr;
  const unsigned short* cp1 = (MODE==5)? (const unsigned short*)B2 + (long)(bn+sr+64)*ldb + sc : nullptr;

  // stage current pointer position into LDS buffer `buf`, then advance ptrs
  auto STAGE = [&](int buf){
    GLL16(ap0, &As[buf][wv*512]);  GLL16(ap1, &As[buf][wv*512+2048]);
    GLL16(bp0, &Bs[buf][wv*512]);  GLL16(bp1, &Bs[buf][wv*512+2048]);
    if (MODE==5){
      GLL16(cp0, &Bs2[buf][wv*512]); GLL16(cp1, &Bs2[buf][wv*512+2048]);
      cp0+=32; cp1+=32;
    }
    ap0+=32; ap1+=32; bp0+=32; bp1+=32;
  };
  auto COMPUTE = [&](int buf){
    bf16x8 af[4], bfr[4];
#pragma unroll
    for (int i=0;i<4;i++) af[i]  = *(const bf16x8*)&As[buf][(wm+i*16+fr)*32 + fq*8];
#pragma unroll
    for (int j=0;j<4;j++) bfr[j] = *(const bf16x8*)&Bs[buf][(wn+j*16+fr)*32 + fq*8];
#pragma unroll
    for (int i=0;i<4;i++)
#pragma unroll
      for (int j=0;j<4;j++)
        acc[i][j] = __builtin_amdgcn_mfma_f32_16x16x32_bf16(af[i], bfr[j], acc[i][j], 0,0,0);
    if (MODE==5){
      bf16x8 bg[4];
#pragma unroll
      for (int j=0;j<4;j++) bg[j] = *(const bf16x8*)&Bs2[buf][(wn+j*16+fr)*32 + fq*8];
#pragma unroll
      for (int i=0;i<4;i++)
#pragma unroll
        for (int j=0;j<4;j++)
          acc2[i][j] = __builtin_amdgcn_mfma_f32_16x16x32_bf16(af[i], bg[j], acc2[i][j], 0,0,0);
    }
  };

  STAGE(0);
  __syncthreads();                      // tile 0 resident (vmcnt drained at barrier)
  for (int k0=0;k0<K;k0+=64){
    STAGE(1);                           // next tile in flight during COMPUTE(0)
    COMPUTE(0);
    __syncthreads();                    // buf0 reads done + buf1 loads landed
    if (k0+64<K) STAGE(0);              // tile k+2 in flight during COMPUTE(1)
    COMPUTE(1);
    if (k0+64<K) __syncthreads();       // buf1 reads done + buf0 loads landed
  }

  bf16* outp = outb ? outb + (long)bz*cstr : nullptr;
#pragma unroll
  for (int j=0;j<4;j++){
    const int col = bn+wn+j*16+fr;
    float bv = bias ? bias[col] : 0.0f;
#pragma unroll
    for (int i=0;i<4;i++){
      const int row0 = bm+wm+i*16+fq*4;
#pragma unroll
      for (int rr=0;rr<4;rr++){
        const int row = row0+rr;
        float v = acc[i][j][rr];
        if (MODE==0){ outp[(long)row*ldc+col] = __float2bfloat16(v+bv); }
        else if (MODE==3){ float mv=__bfloat162float(mul[(long)row*ldm+col]);
                           outp[(long)row*ldc+col]=__float2bfloat16(mv*sigf(v+bv)); }
        else if (MODE==4){
               long idx=(long)row*ldx+col;
               float base = xin ? xin[idx] : x32[idx];
               float nv = base + gate[row]*(v+bv);
               x32[idx]=nv;
               if (fout) fout[idx]=nv; }
        else if (MODE==5){ float g = acc2[i][j][rr];
               outp[(long)row*ldc+col]=__float2bfloat16(v*sigf(g)); }
      }
    }
  }
}

// ---------------------------------------------------------------------------
// Fused RMSNorm + per-row scalar gate:  out_bf = rms(x)*nw ; gate[m]=sig(x.gw+gb)
// ---------------------------------------------------------------------------
__global__ __launch_bounds__(256)
void rms_gate_kernel(const float* __restrict__ x, const float* __restrict__ nw,
                     const float* __restrict__ gw, const float* __restrict__ gb,
                     bf16* __restrict__ out, float* __restrict__ gate)
{
  const int m = blockIdx.x, t = threadIdx.x;
  const float* xr = x + (long)m*1536;
  float v[6]; float ss=0.0f, gd=0.0f;
#pragma unroll
  for (int e=0;e<6;e++){ int idx=t+e*256; float xv=xr[idx]; v[e]=xv;
                         ss+=xv*xv; gd+=xv*gw[idx]; }
  for (int o=32;o;o>>=1){ ss+=__shfl_down(ss,o); gd+=__shfl_down(gd,o); }
  __shared__ float r1[4], r2[4]; __shared__ float invs;
  const int lane=t&63, wvi=t>>6;
  if (lane==0){ r1[wvi]=ss; r2[wvi]=gd; }
  __syncthreads();
  if (t==0){
    float S=r1[0]+r1[1]+r1[2]+r1[3], G=r2[0]+r2[1]+r2[2]+r2[3];
    invs = rsqrtf(S*(1.0f/1536.0f) + 1e-6f);
    gate[m] = sigf(G + gb[0]);
  }
  __syncthreads();
  float inv = invs;
#pragma unroll
  for (int e=0;e<6;e++){ int idx=t+e*256;
    out[(long)m*1536+idx] = __float2bfloat16(v[e]*inv*nw[idx]); }
}

// ---------------------------------------------------------------------------
__global__ __launch_bounds__(256)
void router_kernel(const bf16* __restrict__ x, const float* __restrict__ w,
                   const float* __restrict__ bias, float* __restrict__ hwout)
{
  const int m = blockIdx.x, t = threadIdx.x;
  const bf16* xr = x + (long)m*1536;
  float xs[6];
#pragma unroll
  for (int e=0;e<6;e++) xs[e]=__bfloat162float(xr[t*6+e]);
  float p[12];
#pragma unroll
  for (int i=0;i<12;i++){ float s=0;
#pragma unroll
    for (int e=0;e<6;e++) s += xs[e]*w[(long)i*1536 + t*6 + e];
    p[i]=s; }
#pragma unroll
  for (int i=0;i<12;i++)
    for (int o=32;o;o>>=1) p[i]+=__shfl_down(p[i],o);
  __shared__ float red[4][12];
  const int lane=t&63, wvi=t>>6;
  if (lane==0){
#pragma unroll
    for (int i=0;i<12;i++) red[wvi][i]=p[i]; }
  __syncthreads();
  if (t<12){
    float s = red[0][t]+red[1][t]+red[2][t]+red[3][t] + bias[t];
    hwout[(long)m*12+t]=sigf(s);
  }
}

// ---------------------------------------------------------------------------
__global__ __launch_bounds__(256)
void memg_kernel(const bf16* __restrict__ xh, const float* __restrict__ wg,
                 const float* __restrict__ bg, float* __restrict__ memg)
{
  const int t=threadIdx.x, lane=t&63, wvi=t>>6;
  const int m = blockIdx.x*4 + wvi;
  const int h = lane>>4, e0=(lane&15)*8;
  const bf16* xr = xh + (long)m*1536 + 768 + h*128 + e0;
  const float* wr = wg + h*128 + e0;
  float s=0;
#pragma unroll
  for (int e=0;e<8;e++) s += __bfloat162float(xr[e])*wr[e];
#pragma unroll
  for (int o=1;o<16;o<<=1) s += __shfl_xor(s,o);
  if ((lane&15)==0) memg[(long)m*4+h]=sigf(s+bg[h]);
}

// ---------------------------------------------------------------------------
// conv stack stage (bf16 act, fp32 weights): out = h + gelu(dwconv_dil(h)+bias)
// ---------------------------------------------------------------------------
__global__ __launch_bounds__(256)
void convstack_kernel(const bf16* __restrict__ in, bf16* __restrict__ out,
                      const float* __restrict__ w, const float* __restrict__ bias, int dil)
{
  long id = (long)blockIdx.x*256 + threadIdx.x;
  const int m=(int)(id/384);
  const int c=((int)(id%384))*4;
  const int tt = m & 2047;
  float wvv[4][4], bv[4];
#pragma unroll
  for (int cc=0;cc<4;cc++){
    bv[cc]=bias[c+cc];
    float4 wr = *(const float4*)(w + (long)(c+cc)*4);
    wvv[cc][0]=wr.x; wvv[cc][1]=wr.y; wvv[cc][2]=wr.z; wvv[cc][3]=wr.w;
  }
  float accv[4]={0,0,0,0}, h[4]={0,0,0,0};
#pragma unroll
  for (int k=0;k<4;k++){
    int off=(3-k)*dil;
    if (tt-off < 0) continue;
    long idx=(long)(m-off)*1536 + c;
    ushortx4 tv = *(const ushortx4*)((const unsigned short*)in + idx);
    float x0=b2f(tv[0]),x1=b2f(tv[1]),x2=b2f(tv[2]),x3=b2f(tv[3]);
    accv[0]+=x0*wvv[0][k]; accv[1]+=x1*wvv[1][k];
    accv[2]+=x2*wvv[2][k]; accv[3]+=x3*wvv[3][k];
    if (off==0){ h[0]=x0;h[1]=x1;h[2]=x2;h[3]=x3; }
  }
  long oidx=(long)m*1536+c;
  ushortx4 o;
#pragma unroll
  for (int cc=0;cc<4;cc++) o[cc]=f2b(h[cc]+geluf(accv[cc]+bv[cc]));
  *(ushortx4*)((unsigned short*)out + oidx) = o;
}

// ---------------------------------------------------------------------------
// per-head dilated conv stage: out = h + dwconv_d(h) + bias
// final stage fuses mem_out add (heads 6..9) and router gating
// ---------------------------------------------------------------------------
__device__ const int HDILS[12][3] = {
  {1,2,4},{1,1,1},{4,8,16},{8,16,32},{32,64,128},{64,128,256},
  {256,512,1024},{1,100,200},{1,500,1000},{1,1024,2048},{3,9,27},{5,25,125}};

__global__ __launch_bounds__(256)
void headconv_kernel(const bf16* __restrict__ in, bf16* __restrict__ out,
                     const float* __restrict__ wAll, const float* __restrict__ bAll,
                     int stage,
                     const bf16* __restrict__ mout, const float* __restrict__ hwr)
{
  long id = (long)blockIdx.x*256 + threadIdx.x;
  const int m=(int)(id/384);
  const int c=((int)(id%384))*4;
  const int tt = m & 2047;
  const int head=c>>7, ch=c&127;
  const int dil = HDILS[head][stage];
  const float* w  = wAll + (((long)head*3+stage)*128 + ch)*4;
  const float* bb = bAll + ((long)head*3+stage)*128 + ch;
  float wvv[4][4], bv[4];
#pragma unroll
  for (int cc=0;cc<4;cc++){
    bv[cc]=bb[cc];
    float4 wr = *(const float4*)(w + cc*4);
    wvv[cc][0]=wr.x; wvv[cc][1]=wr.y; wvv[cc][2]=wr.z; wvv[cc][3]=wr.w;
  }
  float accv[4]={0,0,0,0}, h[4]={0,0,0,0};
#pragma unroll
  for (int k=0;k<4;k++){
    int off=(3-k)*dil;
    if (tt-off < 0) continue;
    long idx=(long)(m-off)*1536 + c;
    ushortx4 tv = *(const ushortx4*)((const unsigned short*)in + idx);
    float x0=b2f(tv[0]),x1=b2f(tv[1]),x2=b2f(tv[2]),x3=b2f(tv[3]);
    accv[0]+=x0*wvv[0][k]; accv[1]+=x1*wvv[1][k];
    accv[2]+=x2*wvv[2][k]; accv[3]+=x3*wvv[3][k];
    if (off==0){ h[0]=x0;h[1]=x1;h[2]=x2;h[3]=x3; }
  }
  float y[4];
#pragma unroll
  for (int cc=0;cc<4;cc++) y[cc]=h[cc]+accv[cc]+bv[cc];
  long oidx=(long)m*1536+c;
  ushortx4 o;
  if (mout){
    if (head>=6 && head<10){
#pragma unroll
      for (int cc=0;cc<4;cc++)
        y[cc]+=__bfloat162float(mout[(long)m*512 + (head-6)*128 + ch + cc]);
    }
    float g = hwr[(long)m*12+head];
#pragma unroll
    for (int cc=0;cc<4;cc++) o[cc]=f2b(y[cc]*g);
  } else {
#pragma unroll
    for (int cc=0;cc<4;cc++) o[cc]=f2b(y[cc]);
  }
  *(ushortx4*)((unsigned short*)out + oidx) = o;
}

// ---------------------------------------------------------------------------
// Parallelized chunked memory scan.
// The recurrence M_{c+1} = decay_c*M_c + W_c is linear, so split the 32 chunks
// into 8 groups of 4:  pass1 runs group-local scans from M=0 (1024 blocks),
// pass2 combines the 8 group states (tiny), pass3 adds the cross-group
// correction  reads_c += Dcum_c * (q_c @ Minit_g)  and emits bf16.
// ---------------------------------------------------------------------------

// decay[bh*32+c] = 1 - mean_s g ; 512 values
__global__ __launch_bounds__(256)
void decay_kernel(const float* __restrict__ mgp, float* __restrict__ dec)
{
  int i = blockIdx.x*256 + threadIdx.x;
  if (i >= 512) return;
  int c = i&31, bh = i>>5; int b = bh>>2, h = bh&3;
  float s = 0.0f;
  for (int t=0;t<64;t++) s += mgp[((long)b*2048 + c*64 + t)*4 + h];
  dec[i] = 1.0f - s*(1.0f/64.0f);
}

// pass 1: group-local scan. grid = b(4) x h(4) x mb(8) x g(8) = 1024 blocks
__global__ __launch_bounds__(256)
void scan_local_kernel(const bf16* __restrict__ qb, const bf16* __restrict__ kb,
                       const bf16* __restrict__ vb, const float* __restrict__ mgp,
                       const float* __restrict__ dec,
                       float* __restrict__ rdf, float* __restrict__ mfin)
{
  __shared__ __align__(16) unsigned short qsu[64][130];
  __shared__ __align__(16) unsigned short kgu[64][130];
  __shared__ __align__(16) float vv[64][20];
  __shared__ __align__(16) float Ms[128][20];
  __shared__ float gch[64];
  const int bidx = blockIdx.x;
  const int g = bidx&7, mb=(bidx>>3)&7, h=(bidx>>6)&3, b=bidx>>8;
  const int tid = threadIdx.x;
  for (int i=tid;i<128*20;i+=256) (&Ms[0][0])[i]=0.0f;
  const long base = (long)b*2048*512 + h*128;
  const int sR = tid&63, mg0=((tid>>6)&3)*4;
  const int dU = tid&127, mg2=(tid>>7)*8;
  const int bh = b*4+h;
  for (int cc=0;cc<4;cc++){
    const int c = g*4+cc;
    __syncthreads();
    if (tid<64) gch[tid] = mgp[((long)b*2048 + c*64 + tid)*4 + h];
#pragma unroll
    for (int u=0;u<4;u++){
      int vi = tid*4+u;
      int s = vi>>4, d0=(vi&15)*8;
      long ga = base + (long)(c*64+s)*512 + d0;
      ushortx8 qv = *(const ushortx8*)((const unsigned short*)qb + ga);
      ushortx8 kv = *(const ushortx8*)((const unsigned short*)kb + ga);
      unsigned int* qrow = (unsigned int*)&qsu[s][d0];
      unsigned int* krow = (unsigned int*)&kgu[s][d0];
#pragma unroll
      for (int e=0;e<4;e++){
        qrow[e] = (unsigned int)qv[2*e] | ((unsigned int)qv[2*e+1]<<16);
        krow[e] = (unsigned int)kv[2*e] | ((unsigned int)kv[2*e+1]<<16);
      }
    }
    {
      int s = tid>>2, c0=(tid&3)*4;
      long ga = base + (long)(c*64+s)*512 + mb*16 + c0;
      ushortx4 tv = *(const ushortx4*)((const unsigned short*)vb + ga);
#pragma unroll
      for (int e=0;e<4;e++) vv[s][c0+e]=b2f(tv[e]);
    }
    __syncthreads();
    const float decay = dec[bh*32+c];
    float racc[4]={0,0,0,0};
#pragma unroll 4
    for (int d=0;d<128;d+=2){
      unsigned int qp = *(const unsigned int*)&qsu[sR][d];
      float q0 = b2f((unsigned short)(qp&0xffffu));
      float q1 = b2f((unsigned short)(qp>>16));
      floatx4 m0 = *(const floatx4*)&Ms[d][mg0];
      floatx4 m1 = *(const floatx4*)&Ms[d+1][mg0];
      racc[0] += q0*m0[0] + q1*m1[0];
      racc[1] += q0*m0[1] + q1*m1[1];
      racc[2] += q0*m0[2] + q1*m1[2];
      racc[3] += q0*m0[3] + q1*m1[3];
    }
    long ro = base + (long)(c*64+sR)*512 + mb*16 + mg0;
    float4 rv; rv.x=racc[0]; rv.y=racc[1]; rv.z=racc[2]; rv.w=racc[3];
    *(float4*)&rdf[ro] = rv;
    __syncthreads();
    float wacc[8]={0,0,0,0,0,0,0,0};
#pragma unroll 2
    for (int s=0;s<64;s++){
      float kvv = b2f(kgu[s][dU])*gch[s];
      floatx4 v0 = *(const floatx4*)&vv[s][mg2];
      floatx4 v1 = *(const floatx4*)&vv[s][mg2+4];
      wacc[0]+=kvv*v0[0]; wacc[1]+=kvv*v0[1]; wacc[2]+=kvv*v0[2]; wacc[3]+=kvv*v0[3];
      wacc[4]+=kvv*v1[0]; wacc[5]+=kvv*v1[1]; wacc[6]+=kvv*v1[2]; wacc[7]+=kvv*v1[3];
    }
    floatx4 mo0 = *(const floatx4*)&Ms[dU][mg2];
    floatx4 mo1 = *(const floatx4*)&Ms[dU][mg2+4];
#pragma unroll
    for (int r=0;r<4;r++){ mo0[r]=decay*mo0[r]+wacc[r]; mo1[r]=decay*mo1[r]+wacc[4+r]; }
    *(floatx4*)&Ms[dU][mg2]   = mo0;
    *(floatx4*)&Ms[dU][mg2+4] = mo1;
  }
  __syncthreads();
  // write final local state
  float* mf = mfin + ((long)((bh*8+mb)*8+g))*2048;
  for (int i=tid;i<2048;i+=256) mf[i] = Ms[i>>4][i&15];
}

// pass 2: scan of group states. grid = (b,h,mb)=128 blocks.
// minit[blk][g] = state at start of group g (zero for g=0).
__global__ __launch_bounds__(256)
void group_scan_kernel(const float* __restrict__ dec,
                       const float* __restrict__ mfin, float* __restrict__ minit)
{
  const int blk = blockIdx.x; const int bh = blk>>3;
  const int tid = threadIdx.x;
  float M[8];
#pragma unroll
  for (int e=0;e<8;e++) M[e]=0.0f;
  for (int g=0;g<8;g++){
    const float* mf = mfin  + ((long)(blk*8+g))*2048;
    float*       mi = minit + ((long)(blk*8+g))*2048;
    const float* dg = dec + bh*32 + g*4;
    float P = dg[0]*dg[1]*dg[2]*dg[3];
#pragma unroll
    for (int e=0;e<8;e++){
      int i = tid*8+e;
      mi[i] = M[e];
      M[e]  = P*M[e] + mf[i];
    }
  }
}

// pass 3: reads_c += Dcum_c * (q_c @ Minit_g); emit bf16. grid = 1024 blocks.
__global__ __launch_bounds__(256)
void scan_fix_kernel(const bf16* __restrict__ qb, const float* __restrict__ dec,
                     const float* __restrict__ minit, const float* __restrict__ rdf,
                     bf16* __restrict__ rd)
{
  __shared__ __align__(16) unsigned short qsu[64][130];
  __shared__ __align__(16) float Ms[128][20];
  const int bidx = blockIdx.x;
  const int g = bidx&7, mb=(bidx>>3)&7, h=(bidx>>6)&3, b=bidx>>8;
  const int tid = threadIdx.x;
  const int bh = b*4+h;
  if (g){
    const float* mi = minit + ((long)((bh*8+mb)*8+g))*2048;
    for (int i=tid;i<2048;i+=256) Ms[i>>4][i&15] = mi[i];
  }
  const long base = (long)b*2048*512 + h*128;
  const int sR = tid&63, mg0=((tid>>6)&3)*4;
  float Dc = 1.0f;
  for (int cc=0;cc<4;cc++){
    const int c = g*4+cc;
    float racc[4]={0,0,0,0};
    if (g){
      __syncthreads();
#pragma unroll
      for (int u=0;u<4;u++){
        int vi = tid*4+u;
        int s = vi>>4, d0=(vi&15)*8;
        long ga = base + (long)(c*64+s)*512 + d0;
        ushortx8 qv = *(const ushortx8*)((const unsigned short*)qb + ga);
        unsigned int* qrow = (unsigned int*)&qsu[s][d0];
#pragma unroll
        for (int e=0;e<4;e++)
          qrow[e] = (unsigned int)qv[2*e] | ((unsigned int)qv[2*e+1]<<16);
      }
      __syncthreads();
#pragma unroll 4
      for (int d=0;d<128;d+=2){
        unsigned int qp = *(const unsigned int*)&qsu[sR][d];
        float q0 = b2f((unsigned short)(qp&0xffffu));
        float q1 = b2f((unsigned short)(qp>>16));
        floatx4 m0 = *(const floatx4*)&Ms[d][mg0];
        floatx4 m1 = *(const floatx4*)&Ms[d+1][mg0];
        racc[0] += q0*m0[0] + q1*m1[0];
        racc[1] += q0*m0[1] + q1*m1[1];
        racc[2] += q0*m0[2] + q1*m1[2];
        racc[3] += q0*m0[3] + q1*m1[3];
      }
    }
    long ro = base + (long)(c*64+sR)*512 + mb*16 + mg0;
    float4 rv = *(const float4*)&rdf[ro];
    ushortx4 o;
    o[0]=f2b(rv.x + Dc*racc[0]);
    o[1]=f2b(rv.y + Dc*racc[1]);
    o[2]=f2b(rv.z + Dc*racc[2]);
    o[3]=f2b(rv.w + Dc*racc[3]);
    *(ushortx4*)((unsigned short*)rd + ro) = o;
    Dc *= dec[bh*32+c];
  }
}

// ---------------------------------------------------------------------------
extern "C" void kernel_launch(void* const* d_in, const int* in_sizes, int n_in,
                              void* d_out, int out_size, void* d_ws, size_t ws_size,
                              hipStream_t stream)
{
  (void)in_sizes; (void)n_in; (void)out_size; (void)ws_size;
  const int H = 1536, M = 8192;

  const float* x_in     = (const float*)d_in[0];
  const float* norm1_w  = (const float*)d_in[1];
  const float* norm2_w  = (const float*)d_in[2];
  const float* norm3_w  = (const float*)d_in[3];
  const float* cstk_w   = (const float*)d_in[4];
  const float* cstk_b   = (const float*)d_in[5];
  const float* cproj_w  = (const float*)d_in[6];
  const float* cproj_b  = (const float*)d_in[7];
  const float* gproj_w  = (const float*)d_in[8];
  const float* hrout_w  = (const float*)d_in[9];
  const float* hrout_b  = (const float*)d_in[10];
  const float* hconv_w  = (const float*)d_in[11];
  const float* hconv_b  = (const float*)d_in[12];
  const float* mWq      = (const float*)d_in[13];
  const float* mWk      = (const float*)d_in[14];
  const float* mWv      = (const float*)d_in[15];
  const float* mWg_w    = (const float*)d_in[16];
  const float* mWg_b    = (const float*)d_in[17];
  const float* mWout    = (const float*)d_in[18];
  const float* mixg_w   = (const float*)d_in[19];
  const float* mixg_b   = (const float*)d_in[20];
  const float* mix_w    = (const float*)d_in[21];
  const float* mix_b    = (const float*)d_in[22];
  const float* ffin_w   = (const float*)d_in[23];
  const float* ffout_w  = (const float*)d_in[24];
  const float* cgate_w  = (const float*)d_in[25];
  const float* cgate_b  = (const float*)d_in[26];
  const float* sgate_w  = (const float*)d_in[27];
  const float* sgate_b  = (const float*)d_in[28];
  const float* fgate_w  = (const float*)d_in[29];
  const float* fgate_b  = (const float*)d_in[30];

  // ---- workspace layout (~224 MiB peak) ----
  char* W = (char*)d_ws;
  const size_t SZ_X32 = (size_t)M*H*4;   // 48 MiB
  const size_t SZ_BUF = (size_t)M*H*2;   // 24 MiB
  float* x32 = (float*)W;
  char*  P   = W + SZ_X32;
  // packed bf16 weights
  bf16* WB = (bf16*)P;
  const size_t oCproj = 0;
  const size_t oGproj = oCproj + (size_t)H*H;          // 2,359,296
  const size_t oWq    = oGproj + (size_t)2*H*H;        // +4,718,592
  const size_t oWk    = oWq   + 65536;
  const size_t oWv    = oWk   + 65536;
  const size_t oWout  = oWv   + 65536;
  const size_t oMixg  = oWout + 65536;
  const size_t oMix   = oMixg + (size_t)H*H;
  const size_t oFfin  = oMix  + (size_t)H*H;
  const size_t oFfout = oFfin + (size_t)2*6144*H;
  const size_t nWB    = oFfout + (size_t)6144*H;       // 40,370,176 elems
  P += (nWB*2 + 1023) & ~(size_t)1023;
  bf16*  R1  = (bf16*)P;  P += SZ_BUF;
  bf16*  R2  = (bf16*)P;  P += SZ_BUF;
  bf16*  R3  = (bf16*)P;  P += SZ_BUF;
  bf16*  HB  = R2;                      // 48 MiB spanning R2+R3 (stage C)
  bf16*  rdb = (bf16*)P;  P += (size_t)M*512*2;
  bf16*  mob = (bf16*)P;  P += (size_t)M*512*2;
  float* hwr  = (float*)P; P += (size_t)M*12*4;
  float* memg = (float*)P; P += (size_t)M*4*4;
  float* gc   = (float*)P; P += (size_t)M*4;
  float* gs   = (float*)P; P += (size_t)M*4;
  float* gf   = (float*)P; P += (size_t)M*4;
  float* decv = (float*)P; P += 512*4;
  bf16*  qb = R1;                 // stage B aliases (R1 free after gproj GEMM)
  bf16*  kb = R1 + (size_t)M*512;
  bf16*  vb = R1 + (size_t)M*1024;
  // scan scratch aliases (live only between qkv GEMMs and wout GEMM):
  //   rdf  (fp32 local reads, 16 MiB)  -> R3 (dead: stage A done, headconv later)
  //   minit (8 MiB)                    -> R3 + 16 MiB (exact fit: R3 is 24 MiB)
  //   mfin  (8 MiB)                    -> mob (written by wout GEMM afterwards)
  float* rdf   = (float*)R3;
  float* minit = (float*)((char*)R3 + (size_t)16777216);
  float* mfin  = (float*)mob;

  hipStream_t st = stream;
  dim3 blk(256);

  // ---- weight conversion fp32 -> bf16 --------------------------------------
  w2b_kernel<<<(int)((size_t)H*H/2048),      blk, 0, st>>>(cproj_w, WB+oCproj);
  w2b_kernel<<<(int)((size_t)2*H*H/2048),    blk, 0, st>>>(gproj_w, WB+oGproj);
  w2b_kernel<<<32,                            blk, 0, st>>>(mWq,    WB+oWq);
  w2b_kernel<<<32,                            blk, 0, st>>>(mWk,    WB+oWk);
  w2b_kernel<<<32,                            blk, 0, st>>>(mWv,    WB+oWv);
  w2b_kernel<<<32,                            blk, 0, st>>>(mWout,  WB+oWout);
  w2b_kernel<<<(int)((size_t)H*H/2048),      blk, 0, st>>>(mixg_w, WB+oMixg);
  w2b_kernel<<<(int)((size_t)H*H/2048),      blk, 0, st>>>(mix_w,  WB+oMix);
  w2b_kernel<<<(int)((size_t)2*6144*H/2048), blk, 0, st>>>(ffin_w, WB+oFfin);
  w2b_kernel<<<(int)((size_t)6144*H/2048),   blk, 0, st>>>(ffout_w,WB+oFfout);

  // ---- stage A: conv branch -------------------------------------------------
  rms_gate_kernel<<<M, blk, 0, st>>>(x_in, norm1_w, cgate_w, cgate_b, R1, gc);
  convstack_kernel<<<12288, blk, 0, st>>>(R1, R2, cstk_w        , cstk_b      , 1);
  convstack_kernel<<<12288, blk, 0, st>>>(R2, R3, cstk_w + 1*H*4, cstk_b + 1*H, 2);
  convstack_kernel<<<12288, blk, 0, st>>>(R3, R2, cstk_w + 2*H*4, cstk_b + 2*H, 4);
  convstack_kernel<<<12288, blk, 0, st>>>(R2, R3, cstk_w + 3*H*4, cstk_b + 3*H, 8);
  convstack_kernel<<<12288, blk, 0, st>>>(R3, R2, cstk_w + 4*H*4, cstk_b + 4*H, 16);
  convstack_kernel<<<12288, blk, 0, st>>>(R2, R3, cstk_w + 5*H*4, cstk_b + 5*H, 32);
  gemm_bt<4><<<dim3(64,12,1), blk, 0, st>>>(R3,H,0, WB+oCproj,H,0, nullptr, H, cproj_b,
                                            nullptr,0, gc, x_in, x32,H, nullptr, H,0, nullptr);

  // ---- stage B: state branch ------------------------------------------------
  rms_gate_kernel<<<M, blk, 0, st>>>(x32, norm2_w, sgate_w, sgate_b, R1, gs);
  router_kernel<<<M, blk, 0, st>>>(R1, hrout_w, hrout_b, hwr);
  gemm_bt<5><<<dim3(64,12,1), blk, 0, st>>>(R1,H,0, WB+oGproj,H,0, WB+oGproj+(size_t)H*H, H, nullptr,
                                            nullptr,0, nullptr, nullptr, nullptr,0, R2, H,0, nullptr);
  memg_kernel<<<2048, blk, 0, st>>>(R2, mWg_w, mWg_b, memg);
  gemm_bt<0><<<dim3(64,1,4), blk, 0, st>>>(R2+768,H,128, WB+oWq,128,16384, nullptr, 128, nullptr,
                                           nullptr,0, nullptr, nullptr, nullptr,0, qb, 512, 128, nullptr);
  gemm_bt<0><<<dim3(64,1,4), blk, 0, st>>>(R2+768,H,128, WB+oWk,128,16384, nullptr, 128, nullptr,
                                           nullptr,0, nullptr, nullptr, nullptr,0, kb, 512, 128, nullptr);
  gemm_bt<0><<<dim3(64,1,4), blk, 0, st>>>(R2+768,H,128, WB+oWv,128,16384, nullptr, 128, nullptr,
                                           nullptr,0, nullptr, nullptr, nullptr,0, vb, 512, 128, nullptr);
  decay_kernel<<<2, blk, 0, st>>>(memg, decv);
  scan_local_kernel<<<1024, blk, 0, st>>>(qb, kb, vb, memg, decv, rdf, mfin);
  group_scan_kernel<<<128, blk, 0, st>>>(decv, mfin, minit);
  scan_fix_kernel<<<1024, blk, 0, st>>>(qb, decv, minit, rdf, rdb);
  gemm_bt<0><<<dim3(64,1,4), blk, 0, st>>>(rdb,512,128, WB+oWout,128,16384, nullptr, 128, nullptr,
                                           nullptr,0, nullptr, nullptr, nullptr,0, mob, 512, 128, nullptr);
  headconv_kernel<<<12288, blk, 0, st>>>(R2, R3, hconv_w, hconv_b, 0, nullptr, nullptr);
  headconv_kernel<<<12288, blk, 0, st>>>(R3, R2, hconv_w, hconv_b, 1, nullptr, nullptr);
  headconv_kernel<<<12288, blk, 0, st>>>(R2, R3, hconv_w, hconv_b, 2, mob, hwr);
  gemm_bt<3><<<dim3(64,12,1), blk, 0, st>>>(R3,H,0, WB+oMixg,H,0, nullptr, H, mixg_b,
                                            R3,H, nullptr, nullptr, nullptr,0, R2, H,0, nullptr);
  gemm_bt<4><<<dim3(64,12,1), blk, 0, st>>>(R2,H,0, WB+oMix,H,0, nullptr, H, mix_b,
                                            nullptr,0, gs, nullptr, x32,H, nullptr, H,0, nullptr);

  // ---- stage C: FFN (two 3072-col chunks, split-K accumulate) --------------
  rms_gate_kernel<<<M, blk, 0, st>>>(x32, norm3_w, fgate_w, fgate_b, R1, gf);
  for (int c=0;c<2;c++){
    gemm_bt<5><<<dim3(64,24,1), blk, 0, st>>>(R1,H,0,
        WB+oFfin + (size_t)c*3072*H, H,0, WB+oFfin + (size_t)(6144 + c*3072)*H, H, nullptr,
        nullptr,0, nullptr, nullptr, nullptr,0, HB, 3072,0, nullptr);
    gemm_bt<4><<<dim3(64,12,1), blk, 0, st>>>(HB,3072,0, WB+oFfout + (size_t)c*3072,6144,0, nullptr, 3072, nullptr,
        nullptr,0, gf, nullptr, x32,H, nullptr, H,0, (c==1)?(float*)d_out:nullptr);
  }
}

// Round 5
// 1791.802 us; speedup vs baseline: 1.4824x; 1.4824x over previous
//
#include <hip/hip_runtime.h>
#include <hip/hip_bf16.h>
#include <cmath>

typedef __hip_bfloat16 bf16;
typedef __attribute__((ext_vector_type(4))) float floatx4;
typedef __attribute__((ext_vector_type(8))) __bf16 bf16x8;
typedef __attribute__((ext_vector_type(8))) unsigned short ushortx8;
typedef __attribute__((ext_vector_type(4))) unsigned short ushortx4;

#define DEV __device__ __forceinline__

DEV float b2f(unsigned short u){ union{unsigned int i; float f;} v; v.i=((unsigned int)u)<<16; return v.f; }
DEV float sigf(float x){ return 1.0f/(1.0f+__expf(-x)); }
DEV float geluf(float x){ return 0.5f*x*(1.0f+erff(x*0.7071067811865475f)); }
DEV unsigned short f2b(float f){ bf16 b = __float2bfloat16(f); unsigned short u;
                                __builtin_memcpy(&u,&b,2); return u; }

// ---------------------------------------------------------------------------
// fp32 -> bf16 weight convert, 8 elems/thread
// ---------------------------------------------------------------------------
__global__ __launch_bounds__(256)
void w2b_kernel(const float* __restrict__ in, bf16* __restrict__ out)
{
  long i = ((long)blockIdx.x*256 + threadIdx.x)*8;
  float4 a = *(const float4*)(in+i);
  float4 b = *(const float4*)(in+i+4);
  ushortx8 o;
  o[0]=f2b(a.x); o[1]=f2b(a.y); o[2]=f2b(a.z); o[3]=f2b(a.w);
  o[4]=f2b(b.x); o[5]=f2b(b.y); o[6]=f2b(b.z); o[7]=f2b(b.w);
  *(ushortx8*)((unsigned short*)out + i) = o;
}

// ---------------------------------------------------------------------------
// Generic MFMA GEMM:  C[M,N] = A[M,K] * B[N,K]^T  (both K-contiguous, bf16)
// 128x128 tile, BK=32, 256 threads (2x2 waves, each 64x64 via 4x4 16x16x32).
// Reg-staged global->reg->LDS with cross-iteration pipelining (loads issued
// before the barrier). __launch_bounds__(256,2) forces <=256 unified VGPRs
// per lane so MODE5 (128 accumulator regs) still fits 2 waves/SIMD --
// without it MODE5 allocates ~264 and drops to 1 wave/SIMD (zero TLP,
// barrier drains fully exposed; rounds 1-4 all measured ~12% occupancy).
// MODE: 0=plain(+bias)  3=mul*sigmoid(acc+bias)
//       4=resid: x32 = (xin?xin:x32) + gate[row]*(acc+bias); opt fp32 fout store
//       5=GLU: out = accB * sigmoid(accB2)   (dual B tiles)
// ---------------------------------------------------------------------------
template<int MODE>
__global__ __launch_bounds__(256,2)
void gemm_bt(const bf16* __restrict__ A, int lda, long astr,
             const bf16* __restrict__ B, int ldb, long bstr,
             const bf16* __restrict__ B2,
             int K,
             const float* __restrict__ bias,
             const bf16* __restrict__ mul, int ldm,
             const float* __restrict__ gate,
             const float* __restrict__ xin,
             float* __restrict__ x32, int ldx,
             bf16* __restrict__ outb, int ldc, long cstr,
             float* __restrict__ fout)
{
  __shared__ __align__(16) unsigned short As[128*32];
  __shared__ __align__(16) unsigned short Bs[128*32];
  __shared__ __align__(16) unsigned short Bs2[(MODE==5)?128*32:16];
  const int bz = blockIdx.z;
  const unsigned short* Ag = (const unsigned short*)A + (long)bz*astr;
  const unsigned short* Bg = (const unsigned short*)B + (long)bz*bstr;
  const int bm = blockIdx.x*128, bn = blockIdx.y*128;
  const int tid = threadIdx.x, lane = tid&63, wv = tid>>6;
  const int wm = (wv&1)*64, wn = (wv>>1)*64;
  const int fr = lane&15, fq = lane>>4;
  floatx4 acc[4][4];
  floatx4 acc2[(MODE==5)?4:1][(MODE==5)?4:1];
  floatx4 zero = {0.0f,0.0f,0.0f,0.0f};
#pragma unroll
  for (int i=0;i<4;i++)
#pragma unroll
    for (int j=0;j<4;j++) acc[i][j]=zero;
  if (MODE==5){
#pragma unroll
    for (int i=0;i<4;i++)
#pragma unroll
      for (int j=0;j<4;j++) acc2[i][j]=zero;
  }
  const int sr = tid>>2, sc = (tid&3)*8;
  const unsigned short* ap0 = Ag + (long)(bm+sr)*lda + sc;
  const unsigned short* ap1 = Ag + (long)(bm+sr+64)*lda + sc;
  const unsigned short* bp0 = Bg + (long)(bn+sr)*ldb + sc;
  const unsigned short* bp1 = Bg + (long)(bn+sr+64)*ldb + sc;
  const unsigned short* cp0 = (MODE==5)? (const unsigned short*)B2 + (long)(bn+sr)*ldb + sc : nullptr;
  const unsigned short* cp1 = (MODE==5)? (const unsigned short*)B2 + (long)(bn+sr+64)*ldb + sc : nullptr;
  for (int k0=0;k0<K;k0+=32){
    ushortx8 a0 = *(const ushortx8*)ap0;
    ushortx8 a1 = *(const ushortx8*)ap1;
    ushortx8 b0 = *(const ushortx8*)bp0;
    ushortx8 b1 = *(const ushortx8*)bp1;
    ushortx8 c0, c1;
    if (MODE==5){ c0 = *(const ushortx8*)cp0; c1 = *(const ushortx8*)cp1; cp0+=32; cp1+=32; }
    ap0+=32; ap1+=32; bp0+=32; bp1+=32;
    __syncthreads();
    *(ushortx8*)&As[sr*32+sc] = a0;
    *(ushortx8*)&As[(sr+64)*32+sc] = a1;
    *(ushortx8*)&Bs[sr*32+sc] = b0;
    *(ushortx8*)&Bs[(sr+64)*32+sc] = b1;
    if (MODE==5){ *(ushortx8*)&Bs2[sr*32+sc] = c0; *(ushortx8*)&Bs2[(sr+64)*32+sc] = c1; }
    __syncthreads();
    bf16x8 af[4], bfr[4];
#pragma unroll
    for (int i=0;i<4;i++) af[i]  = *(const bf16x8*)&As[(wm+i*16+fr)*32 + fq*8];
#pragma unroll
    for (int j=0;j<4;j++) bfr[j] = *(const bf16x8*)&Bs[(wn+j*16+fr)*32 + fq*8];
#pragma unroll
    for (int i=0;i<4;i++)
#pragma unroll
      for (int j=0;j<4;j++)
        acc[i][j] = __builtin_amdgcn_mfma_f32_16x16x32_bf16(af[i], bfr[j], acc[i][j], 0,0,0);
    if (MODE==5){
      bf16x8 bg[4];
#pragma unroll
      for (int j=0;j<4;j++) bg[j] = *(const bf16x8*)&Bs2[(wn+j*16+fr)*32 + fq*8];
#pragma unroll
      for (int i=0;i<4;i++)
#pragma unroll
        for (int j=0;j<4;j++)
          acc2[i][j] = __builtin_amdgcn_mfma_f32_16x16x32_bf16(af[i], bg[j], acc2[i][j], 0,0,0);
    }
  }
  bf16* outp = outb ? outb + (long)bz*cstr : nullptr;
#pragma unroll
  for (int j=0;j<4;j++){
    const int col = bn+wn+j*16+fr;
    float bv = bias ? bias[col] : 0.0f;
#pragma unroll
    for (int i=0;i<4;i++){
      const int row0 = bm+wm+i*16+fq*4;
#pragma unroll
      for (int rr=0;rr<4;rr++){
        const int row = row0+rr;
        float v = acc[i][j][rr];
        if (MODE==0){ outp[(long)row*ldc+col] = __float2bfloat16(v+bv); }
        else if (MODE==3){ float mv=__bfloat162float(mul[(long)row*ldm+col]);
                           outp[(long)row*ldc+col]=__float2bfloat16(mv*sigf(v+bv)); }
        else if (MODE==4){
               long idx=(long)row*ldx+col;
               float base = xin ? xin[idx] : x32[idx];
               float nv = base + gate[row]*(v+bv);
               x32[idx]=nv;
               if (fout) fout[idx]=nv; }
        else if (MODE==5){ float g = acc2[i][j][rr];
               outp[(long)row*ldc+col]=__float2bfloat16(v*sigf(g)); }
      }
    }
  }
}

// ---------------------------------------------------------------------------
// Fused RMSNorm + per-row scalar gate:  out_bf = rms(x)*nw ; gate[m]=sig(x.gw+gb)
// ---------------------------------------------------------------------------
__global__ __launch_bounds__(256)
void rms_gate_kernel(const float* __restrict__ x, const float* __restrict__ nw,
                     const float* __restrict__ gw, const float* __restrict__ gb,
                     bf16* __restrict__ out, float* __restrict__ gate)
{
  const int m = blockIdx.x, t = threadIdx.x;
  const float* xr = x + (long)m*1536;
  float v[6]; float ss=0.0f, gd=0.0f;
#pragma unroll
  for (int e=0;e<6;e++){ int idx=t+e*256; float xv=xr[idx]; v[e]=xv;
                         ss+=xv*xv; gd+=xv*gw[idx]; }
  for (int o=32;o;o>>=1){ ss+=__shfl_down(ss,o); gd+=__shfl_down(gd,o); }
  __shared__ float r1[4], r2[4]; __shared__ float invs;
  const int lane=t&63, wvi=t>>6;
  if (lane==0){ r1[wvi]=ss; r2[wvi]=gd; }
  __syncthreads();
  if (t==0){
    float S=r1[0]+r1[1]+r1[2]+r1[3], G=r2[0]+r2[1]+r2[2]+r2[3];
    invs = rsqrtf(S*(1.0f/1536.0f) + 1e-6f);
    gate[m] = sigf(G + gb[0]);
  }
  __syncthreads();
  float inv = invs;
#pragma unroll
  for (int e=0;e<6;e++){ int idx=t+e*256;
    out[(long)m*1536+idx] = __float2bfloat16(v[e]*inv*nw[idx]); }
}

// ---------------------------------------------------------------------------
__global__ __launch_bounds__(256)
void router_kernel(const bf16* __restrict__ x, const float* __restrict__ w,
                   const float* __restrict__ bias, float* __restrict__ hwout)
{
  const int m = blockIdx.x, t = threadIdx.x;
  const bf16* xr = x + (long)m*1536;
  float xs[6];
#pragma unroll
  for (int e=0;e<6;e++) xs[e]=__bfloat162float(xr[t*6+e]);
  float p[12];
#pragma unroll
  for (int i=0;i<12;i++){ float s=0;
#pragma unroll
    for (int e=0;e<6;e++) s += xs[e]*w[(long)i*1536 + t*6 + e];
    p[i]=s; }
#pragma unroll
  for (int i=0;i<12;i++)
    for (int o=32;o;o>>=1) p[i]+=__shfl_down(p[i],o);
  __shared__ float red[4][12];
  const int lane=t&63, wvi=t>>6;
  if (lane==0){
#pragma unroll
    for (int i=0;i<12;i++) red[wvi][i]=p[i]; }
  __syncthreads();
  if (t<12){
    float s = red[0][t]+red[1][t]+red[2][t]+red[3][t] + bias[t];
    hwout[(long)m*12+t]=sigf(s);
  }
}

// ---------------------------------------------------------------------------
__global__ __launch_bounds__(256)
void memg_kernel(const bf16* __restrict__ xh, const float* __restrict__ wg,
                 const float* __restrict__ bg, float* __restrict__ memg)
{
  const int t=threadIdx.x, lane=t&63, wvi=t>>6;
  const int m = blockIdx.x*4 + wvi;
  const int h = lane>>4, e0=(lane&15)*8;
  const bf16* xr = xh + (long)m*1536 + 768 + h*128 + e0;
  const float* wr = wg + h*128 + e0;
  float s=0;
#pragma unroll
  for (int e=0;e<8;e++) s += __bfloat162float(xr[e])*wr[e];
#pragma unroll
  for (int o=1;o<16;o<<=1) s += __shfl_xor(s,o);
  if ((lane&15)==0) memg[(long)m*4+h]=sigf(s+bg[h]);
}

// ---------------------------------------------------------------------------
// conv stack stage (bf16 act, fp32 weights): out = h + gelu(dwconv_dil(h)+bias)
// ---------------------------------------------------------------------------
__global__ __launch_bounds__(256)
void convstack_kernel(const bf16* __restrict__ in, bf16* __restrict__ out,
                      const float* __restrict__ w, const float* __restrict__ bias, int dil)
{
  long id = (long)blockIdx.x*256 + threadIdx.x;
  const int m=(int)(id/384);
  const int c=((int)(id%384))*4;
  const int tt = m & 2047;
  float wvv[4][4], bv[4];
#pragma unroll
  for (int cc=0;cc<4;cc++){
    bv[cc]=bias[c+cc];
    float4 wr = *(const float4*)(w + (long)(c+cc)*4);
    wvv[cc][0]=wr.x; wvv[cc][1]=wr.y; wvv[cc][2]=wr.z; wvv[cc][3]=wr.w;
  }
  float accv[4]={0,0,0,0}, h[4]={0,0,0,0};
#pragma unroll
  for (int k=0;k<4;k++){
    int off=(3-k)*dil;
    if (tt-off < 0) continue;
    long idx=(long)(m-off)*1536 + c;
    ushortx4 tv = *(const ushortx4*)((const unsigned short*)in + idx);
    float x0=b2f(tv[0]),x1=b2f(tv[1]),x2=b2f(tv[2]),x3=b2f(tv[3]);
    accv[0]+=x0*wvv[0][k]; accv[1]+=x1*wvv[1][k];
    accv[2]+=x2*wvv[2][k]; accv[3]+=x3*wvv[3][k];
    if (off==0){ h[0]=x0;h[1]=x1;h[2]=x2;h[3]=x3; }
  }
  long oidx=(long)m*1536+c;
  ushortx4 o;
#pragma unroll
  for (int cc=0;cc<4;cc++) o[cc]=f2b(h[cc]+geluf(accv[cc]+bv[cc]));
  *(ushortx4*)((unsigned short*)out + oidx) = o;
}

// ---------------------------------------------------------------------------
// per-head dilated conv stage: out = h + dwconv_d(h) + bias
// final stage fuses mem_out add (heads 6..9) and router gating
// ---------------------------------------------------------------------------
__device__ const int HDILS[12][3] = {
  {1,2,4},{1,1,1},{4,8,16},{8,16,32},{32,64,128},{64,128,256},
  {256,512,1024},{1,100,200},{1,500,1000},{1,1024,2048},{3,9,27},{5,25,125}};

__global__ __launch_bounds__(256)
void headconv_kernel(const bf16* __restrict__ in, bf16* __restrict__ out,
                     const float* __restrict__ wAll, const float* __restrict__ bAll,
                     int stage,
                     const bf16* __restrict__ mout, const float* __restrict__ hwr)
{
  long id = (long)blockIdx.x*256 + threadIdx.x;
  const int m=(int)(id/384);
  const int c=((int)(id%384))*4;
  const int tt = m & 2047;
  const int head=c>>7, ch=c&127;
  const int dil = HDILS[head][stage];
  const float* w  = wAll + (((long)head*3+stage)*128 + ch)*4;
  const float* bb = bAll + ((long)head*3+stage)*128 + ch;
  float wvv[4][4], bv[4];
#pragma unroll
  for (int cc=0;cc<4;cc++){
    bv[cc]=bb[cc];
    float4 wr = *(const float4*)(w + cc*4);
    wvv[cc][0]=wr.x; wvv[cc][1]=wr.y; wvv[cc][2]=wr.z; wvv[cc][3]=wr.w;
  }
  float accv[4]={0,0,0,0}, h[4]={0,0,0,0};
#pragma unroll
  for (int k=0;k<4;k++){
    int off=(3-k)*dil;
    if (tt-off < 0) continue;
    long idx=(long)(m-off)*1536 + c;
    ushortx4 tv = *(const ushortx4*)((const unsigned short*)in + idx);
    float x0=b2f(tv[0]),x1=b2f(tv[1]),x2=b2f(tv[2]),x3=b2f(tv[3]);
    accv[0]+=x0*wvv[0][k]; accv[1]+=x1*wvv[1][k];
    accv[2]+=x2*wvv[2][k]; accv[3]+=x3*wvv[3][k];
    if (off==0){ h[0]=x0;h[1]=x1;h[2]=x2;h[3]=x3; }
  }
  float y[4];
#pragma unroll
  for (int cc=0;cc<4;cc++) y[cc]=h[cc]+accv[cc]+bv[cc];
  long oidx=(long)m*1536+c;
  ushortx4 o;
  if (mout){
    if (head>=6 && head<10){
#pragma unroll
      for (int cc=0;cc<4;cc++)
        y[cc]+=__bfloat162float(mout[(long)m*512 + (head-6)*128 + ch + cc]);
    }
    float g = hwr[(long)m*12+head];
#pragma unroll
    for (int cc=0;cc<4;cc++) o[cc]=f2b(y[cc]*g);
  } else {
#pragma unroll
    for (int cc=0;cc<4;cc++) o[cc]=f2b(y[cc]);
  }
  *(ushortx4*)((unsigned short*)out + oidx) = o;
}

// ---------------------------------------------------------------------------
// Parallelized chunked memory scan.
// The recurrence M_{c+1} = decay_c*M_c + W_c is linear, so split the 32 chunks
// into 8 groups of 4:  pass1 runs group-local scans from M=0 (1024 blocks),
// pass2 combines the 8 group states (tiny), pass3 adds the cross-group
// correction  reads_c += Dcum_c * (q_c @ Minit_g)  and emits bf16.
// ---------------------------------------------------------------------------

// decay[bh*32+c] = 1 - mean_s g ; 512 values
__global__ __launch_bounds__(256)
void decay_kernel(const float* __restrict__ mgp, float* __restrict__ dec)
{
  int i = blockIdx.x*256 + threadIdx.x;
  if (i >= 512) return;
  int c = i&31, bh = i>>5; int b = bh>>2, h = bh&3;
  float s = 0.0f;
  for (int t=0;t<64;t++) s += mgp[((long)b*2048 + c*64 + t)*4 + h];
  dec[i] = 1.0f - s*(1.0f/64.0f);
}

// pass 1: group-local scan. grid = b(4) x h(4) x mb(8) x g(8) = 1024 blocks
__global__ __launch_bounds__(256)
void scan_local_kernel(const bf16* __restrict__ qb, const bf16* __restrict__ kb,
                       const bf16* __restrict__ vb, const float* __restrict__ mgp,
                       const float* __restrict__ dec,
                       float* __restrict__ rdf, float* __restrict__ mfin)
{
  __shared__ __align__(16) unsigned short qsu[64][130];
  __shared__ __align__(16) unsigned short kgu[64][130];
  __shared__ __align__(16) float vv[64][20];
  __shared__ __align__(16) float Ms[128][20];
  __shared__ float gch[64];
  const int bidx = blockIdx.x;
  const int g = bidx&7, mb=(bidx>>3)&7, h=(bidx>>6)&3, b=bidx>>8;
  const int tid = threadIdx.x;
  for (int i=tid;i<128*20;i+=256) (&Ms[0][0])[i]=0.0f;
  const long base = (long)b*2048*512 + h*128;
  const int sR = tid&63, mg0=((tid>>6)&3)*4;
  const int dU = tid&127, mg2=(tid>>7)*8;
  const int bh = b*4+h;
  for (int cc=0;cc<4;cc++){
    const int c = g*4+cc;
    __syncthreads();
    if (tid<64) gch[tid] = mgp[((long)b*2048 + c*64 + tid)*4 + h];
#pragma unroll
    for (int u=0;u<4;u++){
      int vi = tid*4+u;
      int s = vi>>4, d0=(vi&15)*8;
      long ga = base + (long)(c*64+s)*512 + d0;
      ushortx8 qv = *(const ushortx8*)((const unsigned short*)qb + ga);
      ushortx8 kv = *(const ushortx8*)((const unsigned short*)kb + ga);
      unsigned int* qrow = (unsigned int*)&qsu[s][d0];
      unsigned int* krow = (unsigned int*)&kgu[s][d0];
#pragma unroll
      for (int e=0;e<4;e++){
        qrow[e] = (unsigned int)qv[2*e] | ((unsigned int)qv[2*e+1]<<16);
        krow[e] = (unsigned int)kv[2*e] | ((unsigned int)kv[2*e+1]<<16);
      }
    }
    {
      int s = tid>>2, c0=(tid&3)*4;
      long ga = base + (long)(c*64+s)*512 + mb*16 + c0;
      ushortx4 tv = *(const ushortx4*)((const unsigned short*)vb + ga);
#pragma unroll
      for (int e=0;e<4;e++) vv[s][c0+e]=b2f(tv[e]);
    }
    __syncthreads();
    const float decay = dec[bh*32+c];
    float racc[4]={0,0,0,0};
#pragma unroll 4
    for (int d=0;d<128;d+=2){
      unsigned int qp = *(const unsigned int*)&qsu[sR][d];
      float q0 = b2f((unsigned short)(qp&0xffffu));
      float q1 = b2f((unsigned short)(qp>>16));
      floatx4 m0 = *(const floatx4*)&Ms[d][mg0];
      floatx4 m1 = *(const floatx4*)&Ms[d+1][mg0];
      racc[0] += q0*m0[0] + q1*m1[0];
      racc[1] += q0*m0[1] + q1*m1[1];
      racc[2] += q0*m0[2] + q1*m1[2];
      racc[3] += q0*m0[3] + q1*m1[3];
    }
    long ro = base + (long)(c*64+sR)*512 + mb*16 + mg0;
    float4 rv; rv.x=racc[0]; rv.y=racc[1]; rv.z=racc[2]; rv.w=racc[3];
    *(float4*)&rdf[ro] = rv;
    __syncthreads();
    float wacc[8]={0,0,0,0,0,0,0,0};
#pragma unroll 2
    for (int s=0;s<64;s++){
      float kvv = b2f(kgu[s][dU])*gch[s];
      floatx4 v0 = *(const floatx4*)&vv[s][mg2];
      floatx4 v1 = *(const floatx4*)&vv[s][mg2+4];
      wacc[0]+=kvv*v0[0]; wacc[1]+=kvv*v0[1]; wacc[2]+=kvv*v0[2]; wacc[3]+=kvv*v0[3];
      wacc[4]+=kvv*v1[0]; wacc[5]+=kvv*v1[1]; wacc[6]+=kvv*v1[2]; wacc[7]+=kvv*v1[3];
    }
    floatx4 mo0 = *(const floatx4*)&Ms[dU][mg2];
    floatx4 mo1 = *(const floatx4*)&Ms[dU][mg2+4];
#pragma unroll
    for (int r=0;r<4;r++){ mo0[r]=decay*mo0[r]+wacc[r]; mo1[r]=decay*mo1[r]+wacc[4+r]; }
    *(floatx4*)&Ms[dU][mg2]   = mo0;
    *(floatx4*)&Ms[dU][mg2+4] = mo1;
  }
  __syncthreads();
  // write final local state
  float* mf = mfin + ((long)((bh*8+mb)*8+g))*2048;
  for (int i=tid;i<2048;i+=256) mf[i] = Ms[i>>4][i&15];
}

// pass 2: scan of group states. grid = (b,h,mb)=128 blocks.
// minit[blk][g] = state at start of group g (zero for g=0).
__global__ __launch_bounds__(256)
void group_scan_kernel(const float* __restrict__ dec,
                       const float* __restrict__ mfin, float* __restrict__ minit)
{
  const int blk = blockIdx.x; const int bh = blk>>3;
  const int tid = threadIdx.x;
  float M[8];
#pragma unroll
  for (int e=0;e<8;e++) M[e]=0.0f;
  for (int g=0;g<8;g++){
    const float* mf = mfin  + ((long)(blk*8+g))*2048;
    float*       mi = minit + ((long)(blk*8+g))*2048;
    const float* dg = dec + bh*32 + g*4;
    float P = dg[0]*dg[1]*dg[2]*dg[3];
#pragma unroll
    for (int e=0;e<8;e++){
      int i = tid*8+e;
      mi[i] = M[e];
      M[e]  = P*M[e] + mf[i];
    }
  }
}

// pass 3: reads_c += Dcum_c * (q_c @ Minit_g); emit bf16. grid = 1024 blocks.
__global__ __launch_bounds__(256)
void scan_fix_kernel(const bf16* __restrict__ qb, const float* __restrict__ dec,
                     const float* __restrict__ minit, const float* __restrict__ rdf,
                     bf16* __restrict__ rd)
{
  __shared__ __align__(16) unsigned short qsu[64][130];
  __shared__ __align__(16) float Ms[128][20];
  const int bidx = blockIdx.x;
  const int g = bidx&7, mb=(bidx>>3)&7, h=(bidx>>6)&3, b=bidx>>8;
  const int tid = threadIdx.x;
  const int bh = b*4+h;
  if (g){
    const float* mi = minit + ((long)((bh*8+mb)*8+g))*2048;
    for (int i=tid;i<2048;i+=256) Ms[i>>4][i&15] = mi[i];
  }
  const long base = (long)b*2048*512 + h*128;
  const int sR = tid&63, mg0=((tid>>6)&3)*4;
  float Dc = 1.0f;
  for (int cc=0;cc<4;cc++){
    const int c = g*4+cc;
    float racc[4]={0,0,0,0};
    if (g){
      __syncthreads();
#pragma unroll
      for (int u=0;u<4;u++){
        int vi = tid*4+u;
        int s = vi>>4, d0=(vi&15)*8;
        long ga = base + (long)(c*64+s)*512 + d0;
        ushortx8 qv = *(const ushortx8*)((const unsigned short*)qb + ga);
        unsigned int* qrow = (unsigned int*)&qsu[s][d0];
#pragma unroll
        for (int e=0;e<4;e++)
          qrow[e] = (unsigned int)qv[2*e] | ((unsigned int)qv[2*e+1]<<16);
      }
      __syncthreads();
#pragma unroll 4
      for (int d=0;d<128;d+=2){
        unsigned int qp = *(const unsigned int*)&qsu[sR][d];
        float q0 = b2f((unsigned short)(qp&0xffffu));
        float q1 = b2f((unsigned short)(qp>>16));
        floatx4 m0 = *(const floatx4*)&Ms[d][mg0];
        floatx4 m1 = *(const floatx4*)&Ms[d+1][mg0];
        racc[0] += q0*m0[0] + q1*m1[0];
        racc[1] += q0*m0[1] + q1*m1[1];
        racc[2] += q0*m0[2] + q1*m1[2];
        racc[3] += q0*m0[3] + q1*m1[3];
      }
    }
    long ro = base + (long)(c*64+sR)*512 + mb*16 + mg0;
    float4 rv = *(const float4*)&rdf[ro];
    ushortx4 o;
    o[0]=f2b(rv.x + Dc*racc[0]);
    o[1]=f2b(rv.y + Dc*racc[1]);
    o[2]=f2b(rv.z + Dc*racc[2]);
    o[3]=f2b(rv.w + Dc*racc[3]);
    *(ushortx4*)((unsigned short*)rd + ro) = o;
    Dc *= dec[bh*32+c];
  }
}

// ---------------------------------------------------------------------------
extern "C" void kernel_launch(void* const* d_in, const int* in_sizes, int n_in,
                              void* d_out, int out_size, void* d_ws, size_t ws_size,
                              hipStream_t stream)
{
  (void)in_sizes; (void)n_in; (void)out_size; (void)ws_size;
  const int H = 1536, M = 8192;

  const float* x_in     = (const float*)d_in[0];
  const float* norm1_w  = (const float*)d_in[1];
  const float* norm2_w  = (const float*)d_in[2];
  const float* norm3_w  = (const float*)d_in[3];
  const float* cstk_w   = (const float*)d_in[4];
  const float* cstk_b   = (const float*)d_in[5];
  const float* cproj_w  = (const float*)d_in[6];
  const float* cproj_b  = (const float*)d_in[7];
  const float* gproj_w  = (const float*)d_in[8];
  const float* hrout_w  = (const float*)d_in[9];
  const float* hrout_b  = (const float*)d_in[10];
  const float* hconv_w  = (const float*)d_in[11];
  const float* hconv_b  = (const float*)d_in[12];
  const float* mWq      = (const float*)d_in[13];
  const float* mWk      = (const float*)d_in[14];
  const float* mWv      = (const float*)d_in[15];
  const float* mWg_w    = (const float*)d_in[16];
  const float* mWg_b    = (const float*)d_in[17];
  const float* mWout    = (const float*)d_in[18];
  const float* mixg_w   = (const float*)d_in[19];
  const float* mixg_b   = (const float*)d_in[20];
  const float* mix_w    = (const float*)d_in[21];
  const float* mix_b    = (const float*)d_in[22];
  const float* ffin_w   = (const float*)d_in[23];
  const float* ffout_w  = (const float*)d_in[24];
  const float* cgate_w  = (const float*)d_in[25];
  const float* cgate_b  = (const float*)d_in[26];
  const float* sgate_w  = (const float*)d_in[27];
  const float* sgate_b  = (const float*)d_in[28];
  const float* fgate_w  = (const float*)d_in[29];
  const float* fgate_b  = (const float*)d_in[30];

  // ---- workspace layout (~224 MiB peak) ----
  char* W = (char*)d_ws;
  const size_t SZ_X32 = (size_t)M*H*4;   // 48 MiB
  const size_t SZ_BUF = (size_t)M*H*2;   // 24 MiB
  float* x32 = (float*)W;
  char*  P   = W + SZ_X32;
  // packed bf16 weights
  bf16* WB = (bf16*)P;
  const size_t oCproj = 0;
  const size_t oGproj = oCproj + (size_t)H*H;          // 2,359,296
  const size_t oWq    = oGproj + (size_t)2*H*H;        // +4,718,592
  const size_t oWk    = oWq   + 65536;
  const size_t oWv    = oWk   + 65536;
  const size_t oWout  = oWv   + 65536;
  const size_t oMixg  = oWout + 65536;
  const size_t oMix   = oMixg + (size_t)H*H;
  const size_t oFfin  = oMix  + (size_t)H*H;
  const size_t oFfout = oFfin + (size_t)2*6144*H;
  const size_t nWB    = oFfout + (size_t)6144*H;       // 40,370,176 elems
  P += (nWB*2 + 1023) & ~(size_t)1023;
  bf16*  R1  = (bf16*)P;  P += SZ_BUF;
  bf16*  R2  = (bf16*)P;  P += SZ_BUF;
  bf16*  R3  = (bf16*)P;  P += SZ_BUF;
  bf16*  HB  = R2;                      // 48 MiB spanning R2+R3 (stage C)
  bf16*  rdb = (bf16*)P;  P += (size_t)M*512*2;
  bf16*  mob = (bf16*)P;  P += (size_t)M*512*2;
  float* hwr  = (float*)P; P += (size_t)M*12*4;
  float* memg = (float*)P; P += (size_t)M*4*4;
  float* gc   = (float*)P; P += (size_t)M*4;
  float* gs   = (float*)P; P += (size_t)M*4;
  float* gf   = (float*)P; P += (size_t)M*4;
  float* decv = (float*)P; P += 512*4;
  bf16*  qb = R1;                 // stage B aliases (R1 free after gproj GEMM)
  bf16*  kb = R1 + (size_t)M*512;
  bf16*  vb = R1 + (size_t)M*1024;
  // scan scratch aliases (live only between qkv GEMMs and wout GEMM):
  //   rdf  (fp32 local reads, 16 MiB)  -> R3 (dead: stage A done, headconv later)
  //   minit (8 MiB)                    -> R3 + 16 MiB (exact fit: R3 is 24 MiB)
  //   mfin  (8 MiB)                    -> mob (written by wout GEMM afterwards)
  float* rdf   = (float*)R3;
  float* minit = (float*)((char*)R3 + (size_t)16777216);
  float* mfin  = (float*)mob;

  hipStream_t st = stream;
  dim3 blk(256);

  // ---- weight conversion fp32 -> bf16 --------------------------------------
  w2b_kernel<<<(int)((size_t)H*H/2048),      blk, 0, st>>>(cproj_w, WB+oCproj);
  w2b_kernel<<<(int)((size_t)2*H*H/2048),    blk, 0, st>>>(gproj_w, WB+oGproj);
  w2b_kernel<<<32,                            blk, 0, st>>>(mWq,    WB+oWq);
  w2b_kernel<<<32,                            blk, 0, st>>>(mWk,    WB+oWk);
  w2b_kernel<<<32,                            blk, 0, st>>>(mWv,    WB+oWv);
  w2b_kernel<<<32,                            blk, 0, st>>>(mWout,  WB+oWout);
  w2b_kernel<<<(int)((size_t)H*H/2048),      blk, 0, st>>>(mixg_w, WB+oMixg);
  w2b_kernel<<<(int)((size_t)H*H/2048),      blk, 0, st>>>(mix_w,  WB+oMix);
  w2b_kernel<<<(int)((size_t)2*6144*H/2048), blk, 0, st>>>(ffin_w, WB+oFfin);
  w2b_kernel<<<(int)((size_t)6144*H/2048),   blk, 0, st>>>(ffout_w,WB+oFfout);

  // ---- stage A: conv branch -------------------------------------------------
  rms_gate_kernel<<<M, blk, 0, st>>>(x_in, norm1_w, cgate_w, cgate_b, R1, gc);
  convstack_kernel<<<12288, blk, 0, st>>>(R1, R2, cstk_w        , cstk_b      , 1);
  convstack_kernel<<<12288, blk, 0, st>>>(R2, R3, cstk_w + 1*H*4, cstk_b + 1*H, 2);
  convstack_kernel<<<12288, blk, 0, st>>>(R3, R2, cstk_w + 2*H*4, cstk_b + 2*H, 4);
  convstack_kernel<<<12288, blk, 0, st>>>(R2, R3, cstk_w + 3*H*4, cstk_b + 3*H, 8);
  convstack_kernel<<<12288, blk, 0, st>>>(R3, R2, cstk_w + 4*H*4, cstk_b + 4*H, 16);
  convstack_kernel<<<12288, blk, 0, st>>>(R2, R3, cstk_w + 5*H*4, cstk_b + 5*H, 32);
  gemm_bt<4><<<dim3(64,12,1), blk, 0, st>>>(R3,H,0, WB+oCproj,H,0, nullptr, H, cproj_b,
                                            nullptr,0, gc, x_in, x32,H, nullptr, H,0, nullptr);

  // ---- stage B: state branch ------------------------------------------------
  rms_gate_kernel<<<M, blk, 0, st>>>(x32, norm2_w, sgate_w, sgate_b, R1, gs);
  router_kernel<<<M, blk, 0, st>>>(R1, hrout_w, hrout_b, hwr);
  gemm_bt<5><<<dim3(64,12,1), blk, 0, st>>>(R1,H,0, WB+oGproj,H,0, WB+oGproj+(size_t)H*H, H, nullptr,
                                            nullptr,0, nullptr, nullptr, nullptr,0, R2, H,0, nullptr);
  memg_kernel<<<2048, blk, 0, st>>>(R2, mWg_w, mWg_b, memg);
  gemm_bt<0><<<dim3(64,1,4), blk, 0, st>>>(R2+768,H,128, WB+oWq,128,16384, nullptr, 128, nullptr,
                                           nullptr,0, nullptr, nullptr, nullptr,0, qb, 512, 128, nullptr);
  gemm_bt<0><<<dim3(64,1,4), blk, 0, st>>>(R2+768,H,128, WB+oWk,128,16384, nullptr, 128, nullptr,
                                           nullptr,0, nullptr, nullptr, nullptr,0, kb, 512, 128, nullptr);
  gemm_bt<0><<<dim3(64,1,4), blk, 0, st>>>(R2+768,H,128, WB+oWv,128,16384, nullptr, 128, nullptr,
                                           nullptr,0, nullptr, nullptr, nullptr,0, vb, 512, 128, nullptr);
  decay_kernel<<<2, blk, 0, st>>>(memg, decv);
  scan_local_kernel<<<1024, blk, 0, st>>>(qb, kb, vb, memg, decv, rdf, mfin);
  group_scan_kernel<<<128, blk, 0, st>>>(decv, mfin, minit);
  scan_fix_kernel<<<1024, blk, 0, st>>>(qb, decv, minit, rdf, rdb);
  gemm_bt<0><<<dim3(64,1,4), blk, 0, st>>>(rdb,512,128, WB+oWout,128,16384, nullptr, 128, nullptr,
                                           nullptr,0, nullptr, nullptr, nullptr,0, mob, 512, 128, nullptr);
  headconv_kernel<<<12288, blk, 0, st>>>(R2, R3, hconv_w, hconv_b, 0, nullptr, nullptr);
  headconv_kernel<<<12288, blk, 0, st>>>(R3, R2, hconv_w, hconv_b, 1, nullptr, nullptr);
  headconv_kernel<<<12288, blk, 0, st>>>(R2, R3, hconv_w, hconv_b, 2, mob, hwr);
  gemm_bt<3><<<dim3(64,12,1), blk, 0, st>>>(R3,H,0, WB+oMixg,H,0, nullptr, H, mixg_b,
                                            R3,H, nullptr, nullptr, nullptr,0, R2, H,0, nullptr);
  gemm_bt<4><<<dim3(64,12,1), blk, 0, st>>>(R2,H,0, WB+oMix,H,0, nullptr, H, mix_b,
                                            nullptr,0, gs, nullptr, x32,H, nullptr, H,0, nullptr);

  // ---- stage C: FFN (two 3072-col chunks, split-K accumulate) --------------
  rms_gate_kernel<<<M, blk, 0, st>>>(x32, norm3_w, fgate_w, fgate_b, R1, gf);
  for (int c=0;c<2;c++){
    gemm_bt<5><<<dim3(64,24,1), blk, 0, st>>>(R1,H,0,
        WB+oFfin + (size_t)c*3072*H, H,0, WB+oFfin + (size_t)(6144 + c*3072)*H, H, nullptr,
        nullptr,0, nullptr, nullptr, nullptr,0, HB, 3072,0, nullptr);
    gemm_bt<4><<<dim3(64,12,1), blk, 0, st>>>(HB,3072,0, WB+oFfout + (size_t)c*3072,6144,0, nullptr, 3072, nullptr,
        nullptr,0, gf, nullptr, x32,H, nullptr, H,0, (c==1)?(float*)d_out:nullptr);
  }
}